// Round 4
// baseline (7408.002 us; speedup 1.0000x reference)
//
#include <hip/hip_runtime.h>
#include <cstdint>
#include <cstddef>

#define HDIM 2048
#define VOCAB 32000
#define BT 4096      // B*T tokens
#define NVB 125      // VOCAB / 256
#define BETA_F 0.1f
#define SCALE_X 16.0f
#define SCALE_W 64.0f
#define INV_SC (1.0f / (SCALE_X * SCALE_W))

typedef float f32x4 __attribute__((ext_vector_type(4)));
typedef long lx2 __attribute__((ext_vector_type(2)));

// ---------------------------------------------------------------- helpers
__device__ __forceinline__ void async_lds16(const void* g, void* l) {
  __builtin_amdgcn_global_load_lds(
      (__attribute__((address_space(1))) void*)g,
      (__attribute__((address_space(3))) void*)l,
      16, 0, 0);
}

#define BAR() __builtin_amdgcn_s_barrier()
#define LGKM0() do { asm volatile("s_waitcnt lgkmcnt(0)" ::: "memory"); \
                     __builtin_amdgcn_sched_barrier(0); } while (0)
#define VMCNT(n) do { asm volatile("s_waitcnt vmcnt(" #n ")" ::: "memory"); \
                      __builtin_amdgcn_sched_barrier(0); } while (0)

// ---------------------------------------------------------------- cast fp32 -> fp8 e4m3 (16 elems/thread), scaled
__global__ void cast_fp8_kernel(const float* __restrict__ src,
                                uint4* __restrict__ dst, int n16, float scale) {
  int i = blockIdx.x * blockDim.x + threadIdx.x;
  int stride = gridDim.x * blockDim.x;
  for (; i < n16; i += stride) {
    const float4* s = (const float4*)src + (size_t)i * 4;
    uint4 o;
    {
      float4 a = s[0];
      int r = __builtin_amdgcn_cvt_pk_fp8_f32(a.x * scale, a.y * scale, 0, false);
      o.x = __builtin_amdgcn_cvt_pk_fp8_f32(a.z * scale, a.w * scale, r, true);
    }
    {
      float4 a = s[1];
      int r = __builtin_amdgcn_cvt_pk_fp8_f32(a.x * scale, a.y * scale, 0, false);
      o.y = __builtin_amdgcn_cvt_pk_fp8_f32(a.z * scale, a.w * scale, r, true);
    }
    {
      float4 a = s[2];
      int r = __builtin_amdgcn_cvt_pk_fp8_f32(a.x * scale, a.y * scale, 0, false);
      o.z = __builtin_amdgcn_cvt_pk_fp8_f32(a.z * scale, a.w * scale, r, true);
    }
    {
      float4 a = s[3];
      int r = __builtin_amdgcn_cvt_pk_fp8_f32(a.x * scale, a.y * scale, 0, false);
      o.w = __builtin_amdgcn_cvt_pk_fp8_f32(a.z * scale, a.w * scale, r, true);
    }
    dst[i] = o;
  }
}

// ---------------------------------------------------------------- 256x256 8-phase fp8 GEMM + LSE partials
// LDS half-tile: [row(128)][4 chunks x 16B]. Chunk c of a row's 64-B K-slab holds
// [kk0-slot-c (8B) | kk1-slot-c (8B)] by K-permutation (dot product is K-order
// invariant; A and B use the same permutation). One ds_read_b128 per row yields
// BOTH kk fragments at the R2-verified conflict-free address pattern.
// Swizzle: physical = logical ^ (((row>>3)&1)<<5); staging source pre-swizzled.
__global__ __launch_bounds__(512, 4) void gemm_lse256(
    const unsigned char* __restrict__ Xq,
    const unsigned char* __restrict__ Xrq,
    const unsigned char* __restrict__ Wq,
    const unsigned char* __restrict__ Wrq,
    float2* __restrict__ part) {
  __shared__ __align__(16) char lds[2][2][2][8192];

  const int tid = threadIdx.x;
  const int lane = tid & 63;
  const int w = tid >> 6;        // wave 0..7
  const int wm = w >> 2;         // 0..1 : M-half owner
  const int wn = w & 3;          // 0..3 : N-quarter owner
  const int which = blockIdx.y;  // 0 = policy, 1 = reference

  // XCD-aware bijective swizzle: 2000 blocks = 8 XCDs x 250, mb fastest within chunk.
  const int lin = blockIdx.x;
  const int nl = (lin & 7) * 250 + (lin >> 3);
  const int mb = nl & 15;        // 0..15
  const int nb = nl >> 4;        // 0..124

  const unsigned char* A = which ? Xrq : Xq;
  const unsigned char* B = which ? Wrq : Wq;
  float2* pp = part + (size_t)which * BT * NVB;

  // ---- staging addressing (source pre-swizzled to undo read-side XOR) ----
  const int lanep = lane ^ ((lane & 32) >> 4);
  const int rw = w * 16 + (lanep >> 2);     // row within 128-row half
  const int cw = (lanep & 3) * 16;          // byte col within 64-B K-slab
  const unsigned char* Ag = A + (size_t)(mb * 256 + rw) * HDIM + cw;
  const unsigned char* Bg = B + (size_t)(nb * 256 + rw) * HDIM + cw;

#define STAGE(opsel, buf, h, T) do {                                          \
    const unsigned char* _g = (opsel) ? Bg : Ag;                              \
    async_lds16(_g + (size_t)(h) * 128 * HDIM + (T) * 64,                     \
                &lds[buf][opsel][h][0] + w * 1024);                           \
  } while (0)

  // ---- paired fragment read (swizzled b128 -> kk0 + kk1) ----
  const int l15 = lane & 15;
  const int kbyte = (lane >> 4) * 16;
#define FRAGP(d0, d1, halfptr, row) do {                                      \
    int _r = (row);                                                           \
    int _L = _r * 64 + kbyte;                                                 \
    lx2 _v = *(const lx2*)((halfptr) + (_L ^ (((_r >> 3) & 1) << 5)));        \
    d0 = _v.x; d1 = _v.y;                                                     \
  } while (0)

  const char* A0h = &lds[0][0][wm][0];
  const char* A1h = &lds[1][0][wm][0];
  const char* B0h = &lds[0][1][wn >> 1][0];
  const char* B1h = &lds[1][1][wn >> 1][0];
  const int brow = (wn & 1) * 64;

  f32x4 acc[8][4] = {};
  long aF[4][2], bF[4][2];

#define READ_A(base, mi0) do {                                                \
    _Pragma("unroll") for (int mi = 0; mi < 4; ++mi)                          \
      FRAGP(aF[mi][0], aF[mi][1], base, ((mi0) + mi) * 16 + l15);             \
  } while (0)
#define READ_B(base) do {                                                     \
    _Pragma("unroll") for (int ni = 0; ni < 4; ++ni)                          \
      FRAGP(bF[ni][0], bF[ni][1], base, brow + ni * 16 + l15);                \
  } while (0)
#define MFMA_Q(MI0, NI0) do {                                                 \
    __builtin_amdgcn_s_setprio(1);                                            \
    _Pragma("unroll") for (int kk = 0; kk < 2; ++kk)                          \
    _Pragma("unroll") for (int mi = 0; mi < 4; ++mi)                          \
    _Pragma("unroll") for (int ni = 0; ni < 2; ++ni)                          \
      acc[(MI0) + mi][(NI0) + ni] = __builtin_amdgcn_mfma_f32_16x16x32_fp8_fp8( \
          aF[mi][kk], bF[(NI0) + ni][kk], acc[(MI0) + mi][(NI0) + ni], 0, 0, 0); \
    __builtin_amdgcn_s_setprio(0);                                            \
  } while (0)

  // ---- prologue: tile0 (4 halves) + tile1 (B0,B1,A0); A1(t1) staged at iter0 ph1
  STAGE(0, 0, 0, 0); STAGE(0, 0, 1, 0); STAGE(1, 0, 0, 0); STAGE(1, 0, 1, 0);
  STAGE(1, 1, 0, 1); STAGE(1, 1, 1, 1); STAGE(0, 1, 0, 1);
  VMCNT(3);                      // tile0's 4 ops done; t1's 3 in flight
  BAR();

  // ---- main loop: 16 iterations, 2 K-tiles each (tiles 0..31) ----
  for (int i = 0; i < 16; ++i) {
    const int t1 = 2 * i + 1;
    const int se = (2 * i + 2 > 30) ? 30 : 2 * i + 2;  // even stage tile (buf0)
    const int so = (2 * i + 3 > 31) ? 31 : 2 * i + 3;  // odd  stage tile (buf1)

    // phase 1: q0 of tile t0 (buf0)
    READ_A(A0h, 0);
    READ_B(B0h);
    STAGE(0, 1, 1, t1);          // A-half1 of t1
    BAR(); LGKM0();
    MFMA_Q(0, 0);
    BAR();

    // phase 2
    STAGE(1, 0, 0, se);          // B-half0(se)
    BAR(); LGKM0();
    MFMA_Q(0, 2);
    BAR();

    // phase 3
    READ_A(A0h, 4);
    STAGE(1, 0, 1, se);          // B-half1(se)
    BAR(); LGKM0();
    MFMA_Q(4, 0);
    BAR();

    // phase 4
    STAGE(0, 0, 0, se);          // A-half0(se)
    VMCNT(3);                    // tile t1 fully landed
    BAR();
    MFMA_Q(4, 2);
    BAR();

    // phase 5: q0 of tile t1 (buf1)
    READ_A(A1h, 0);
    READ_B(B1h);
    STAGE(0, 0, 1, se);          // A-half1(se)
    BAR(); LGKM0();
    MFMA_Q(0, 0);
    BAR();

    // phase 6
    STAGE(1, 1, 0, so);          // B-half0(so)
    BAR(); LGKM0();
    MFMA_Q(0, 2);
    BAR();

    // phase 7
    READ_A(A1h, 4);
    STAGE(1, 1, 1, so);          // B-half1(so)
    BAR(); LGKM0();
    MFMA_Q(4, 0);
    BAR();

    // phase 8
    STAGE(0, 1, 0, so);          // A-half0(so)
    VMCNT(3);                    // tile se fully landed
    BAR();
    MFMA_Q(4, 2);
    BAR();
  }
  VMCNT(0);                      // drain redundant tail re-stages before LDS reuse
  BAR();

  // ---- fused LSE epilogue over this block's 256 vocab cols ----
  // C/D layout: col = lane&15, row = (lane>>4)*4 + reg. Un-scale by INV_SC.
  float* red = (float*)&lds[0][0][0][0];
#pragma unroll
  for (int mi = 0; mi < 8; ++mi) {
#pragma unroll
    for (int r = 0; r < 4; ++r) {
      float v0 = acc[mi][0][r] * INV_SC;
      float v1 = acc[mi][1][r] * INV_SC;
      float v2 = acc[mi][2][r] * INV_SC;
      float v3 = acc[mi][3][r] * INV_SC;
      float m = fmaxf(fmaxf(v0, v1), fmaxf(v2, v3));
#pragma unroll
      for (int o = 1; o < 16; o <<= 1) m = fmaxf(m, __shfl_xor(m, o, 64));
      float s = __expf(v0 - m) + __expf(v1 - m) + __expf(v2 - m) + __expf(v3 - m);
#pragma unroll
      for (int o = 1; o < 16; o <<= 1) s += __shfl_xor(s, o, 64);
      if (l15 == 0) {
        int row = wm * 128 + mi * 16 + (lane >> 4) * 4 + r;
        red[wn * 256 + row] = m;
        red[1024 + wn * 256 + row] = s;
      }
    }
  }
  __syncthreads();
  if (tid < 256) {
    float m0 = red[tid], m1 = red[256 + tid], m2 = red[512 + tid], m3 = red[768 + tid];
    float M = fmaxf(fmaxf(m0, m1), fmaxf(m2, m3));
    float S = red[1024 + tid] * __expf(m0 - M) + red[1280 + tid] * __expf(m1 - M) +
              red[1536 + tid] * __expf(m2 - M) + red[1792 + tid] * __expf(m3 - M);
    pp[(size_t)(mb * 256 + tid) * NVB + nb] = make_float2(M, S);
  }
#undef STAGE
#undef FRAGP
#undef READ_A
#undef READ_B
#undef MFMA_Q
}

// ---------------------------------------------------------------- exact fp32 target logit: dot(x, W[y])
__global__ void target_logit(const float* __restrict__ x, const float* __restrict__ xr,
                             const float* __restrict__ W, const float* __restrict__ Wr,
                             const int* __restrict__ y, float* __restrict__ tlog) {
  int wid = (blockIdx.x * blockDim.x + threadIdx.x) >> 6;  // 0..8191
  int lane = threadIdx.x & 63;
  int which = wid >> 12;
  int tok = wid & 4095;
  int yy = y[tok];
  int ys = (yy == -100) ? 0 : yy;
  const float* xv = (which ? xr : x) + (size_t)tok * HDIM;
  const float* wv = (which ? Wr : W) + (size_t)ys * HDIM;
  const float4* x4 = (const float4*)xv;
  const float4* w4 = (const float4*)wv;
  float sum = 0.f;
  for (int i = lane; i < HDIM / 4; i += 64) {
    float4 a = x4[i], b = w4[i];
    sum += a.x * b.x + a.y * b.y + a.z * b.z + a.w * b.w;
  }
#pragma unroll
  for (int o = 1; o < 64; o <<= 1) sum += __shfl_xor(sum, o, 64);
  if (lane == 0) tlog[wid] = sum;
}

// ---------------------------------------------------------------- merge partials -> per-token logp
__global__ void lse_combine(const float2* __restrict__ part,
                            const float* __restrict__ tlog,
                            float* __restrict__ ptok) {
  int wid = (blockIdx.x * blockDim.x + threadIdx.x) >> 6;  // 0..8191
  int lane = threadIdx.x & 63;
  const float2* p = part + (size_t)wid * NVB;
  float m = -INFINITY, s = 0.f;
  for (int i = lane; i < NVB; i += 64) {
    float2 v = p[i];
    float M = fmaxf(m, v.x);
    s = s * __expf(m - M) + v.y * __expf(v.x - M);
    m = M;
  }
#pragma unroll
  for (int o = 1; o < 64; o <<= 1) {
    float mo = __shfl_xor(m, o, 64);
    float so = __shfl_xor(s, o, 64);
    float M = fmaxf(m, mo);
    s = s * __expf(m - M) + so * __expf(mo - M);
    m = M;
  }
  if (lane == 0) ptok[wid] = tlog[wid] - (m + logf(s));
}

// ---------------------------------------------------------------- masked per-seq mean + DPO loss
__global__ void final_loss(const float* __restrict__ ptok,
                           const int* __restrict__ y, float* __restrict__ out) {
  __shared__ float rs[256];
  __shared__ float rc[256];
  __shared__ float seq[8];
  int tid = threadIdx.x;
  for (int s = 0; s < 8; ++s) {
    int which = s >> 2, b = s & 3;
    float lsum = 0.f, lcnt = 0.f;
    for (int t = tid; t < 1024; t += 256) {
      int yy = y[b * 1024 + t];
      if (yy != -100) {
        lsum += ptok[which * 4096 + b * 1024 + t];
        lcnt += 1.f;
      }
    }
    rs[tid] = lsum; rc[tid] = lcnt;
    __syncthreads();
    for (int o = 128; o > 0; o >>= 1) {
      if (tid < o) { rs[tid] += rs[tid + o]; rc[tid] += rc[tid + o]; }
      __syncthreads();
    }
    if (tid == 0) seq[s] = rs[0] / rc[0];
    __syncthreads();
  }
  if (tid == 0) {
    float d0 = BETA_F * ((seq[0] - seq[4]) - (seq[2] - seq[6]));
    float d1 = BETA_F * ((seq[1] - seq[5]) - (seq[3] - seq[7]));
    auto sp = [](float a) { return fmaxf(a, 0.f) + log1pf(expf(-fabsf(a))); };
    out[0] = (sp(-d0) + sp(-d1)) * 0.5f;
  }
}

// ---------------------------------------------------------------- launch
extern "C" void kernel_launch(void* const* d_in, const int* in_sizes, int n_in,
                              void* d_out, int out_size, void* d_ws, size_t ws_size,
                              hipStream_t stream) {
  const float* x   = (const float*)d_in[0];
  const float* xr  = (const float*)d_in[1];
  const int*   y   = (const int*)d_in[2];
  const float* Wf  = (const float*)d_in[3];
  const float* Wrf = (const float*)d_in[4];
  float* out = (float*)d_out;

  char* ws = (char*)d_ws;
  size_t off = 0;
  auto alloc = [&](size_t bytes) -> void* {
    void* p = ws + off;
    off = (off + bytes + 255) & ~(size_t)255;
    return p;
  };
  unsigned char* Xq  = (unsigned char*)alloc((size_t)BT * HDIM);
  unsigned char* Xrq = (unsigned char*)alloc((size_t)BT * HDIM);
  unsigned char* Wq  = (unsigned char*)alloc((size_t)VOCAB * HDIM);
  unsigned char* Wrq = (unsigned char*)alloc((size_t)VOCAB * HDIM);
  float2* part = (float2*)alloc((size_t)2 * BT * NVB * sizeof(float2));
  float*  tlog = (float*)alloc((size_t)2 * BT * sizeof(float));
  float*  ptok = (float*)alloc((size_t)2 * BT * sizeof(float));

  cast_fp8_kernel<<<2048, 256, 0, stream>>>(x,  (uint4*)Xq,  BT * HDIM / 16, SCALE_X);
  cast_fp8_kernel<<<2048, 256, 0, stream>>>(xr, (uint4*)Xrq, BT * HDIM / 16, SCALE_X);
  cast_fp8_kernel<<<2048, 256, 0, stream>>>(Wf,  (uint4*)Wq,  VOCAB * HDIM / 16, SCALE_W);
  cast_fp8_kernel<<<2048, 256, 0, stream>>>(Wrf, (uint4*)Wrq, VOCAB * HDIM / 16, SCALE_W);

  dim3 gg(2000, 2);
  gemm_lse256<<<gg, 512, 0, stream>>>(Xq, Xrq, Wq, Wrq, part);

  target_logit<<<2048, 256, 0, stream>>>(x, xr, Wf, Wrf, y, tlog);
  lse_combine<<<2048, 256, 0, stream>>>(part, tlog, ptok);
  final_loss<<<1, 256, 0, stream>>>(ptok, y, out);
}

// Round 5
// 986.461 us; speedup vs baseline: 7.5097x; 7.5097x over previous
//
#include <hip/hip_runtime.h>
#include <cstdint>
#include <cstddef>

#define HDIM 2048
#define VOCAB 32000
#define BT 4096      // B*T tokens
#define NVB 125      // VOCAB / 256
#define BETA_F 0.1f
#define SCALE_X 16.0f
#define SCALE_W 64.0f
#define INV_SC (1.0f / (SCALE_X * SCALE_W))

typedef float f32x4 __attribute__((ext_vector_type(4)));
typedef long lx2 __attribute__((ext_vector_type(2)));

// ---------------------------------------------------------------- helpers
__device__ __forceinline__ void async_lds16(const void* g, void* l) {
  __builtin_amdgcn_global_load_lds(
      (__attribute__((address_space(1))) void*)g,
      (__attribute__((address_space(3))) void*)l,
      16, 0, 0);
}

#define BAR() __builtin_amdgcn_s_barrier()
#define LGKM0() do { asm volatile("s_waitcnt lgkmcnt(0)" ::: "memory"); \
                     __builtin_amdgcn_sched_barrier(0); } while (0)
#define VMCNT(n) do { asm volatile("s_waitcnt vmcnt(" #n ")" ::: "memory"); \
                      __builtin_amdgcn_sched_barrier(0); } while (0)

// ---------------------------------------------------------------- cast fp32 -> fp8 e4m3 (16 elems/thread), scaled
__global__ void cast_fp8_kernel(const float* __restrict__ src,
                                uint4* __restrict__ dst, int n16, float scale) {
  int i = blockIdx.x * blockDim.x + threadIdx.x;
  int stride = gridDim.x * blockDim.x;
  for (; i < n16; i += stride) {
    const float4* s = (const float4*)src + (size_t)i * 4;
    uint4 o;
    {
      float4 a = s[0];
      int r = __builtin_amdgcn_cvt_pk_fp8_f32(a.x * scale, a.y * scale, 0, false);
      o.x = __builtin_amdgcn_cvt_pk_fp8_f32(a.z * scale, a.w * scale, r, true);
    }
    {
      float4 a = s[1];
      int r = __builtin_amdgcn_cvt_pk_fp8_f32(a.x * scale, a.y * scale, 0, false);
      o.y = __builtin_amdgcn_cvt_pk_fp8_f32(a.z * scale, a.w * scale, r, true);
    }
    {
      float4 a = s[2];
      int r = __builtin_amdgcn_cvt_pk_fp8_f32(a.x * scale, a.y * scale, 0, false);
      o.z = __builtin_amdgcn_cvt_pk_fp8_f32(a.z * scale, a.w * scale, r, true);
    }
    {
      float4 a = s[3];
      int r = __builtin_amdgcn_cvt_pk_fp8_f32(a.x * scale, a.y * scale, 0, false);
      o.w = __builtin_amdgcn_cvt_pk_fp8_f32(a.z * scale, a.w * scale, r, true);
    }
    dst[i] = o;
  }
}

// ---------------------------------------------------------------- 256x256 8-phase fp8 GEMM + LSE partials
// LDS half-tile: [row(128)][4 chunks x 16B]. Chunk c of a row's 64-B K-slab holds
// [kk0-slot-c (8B) | kk1-slot-c (8B)] by K-permutation (dot product is K-order
// invariant; A and B use the same permutation). One ds_read_b128 per row yields
// BOTH kk fragments at the R2-verified conflict-free address pattern.
// Swizzle: physical = logical ^ (((row>>3)&1)<<5); staging source pre-swizzled.
//
// NOTE launch_bounds(512,2): 1 block/CU by design. acc[8][4] = 128 f32 regs;
// capping VGPRs below ~232 (R4's (512,4) experiment) spills accumulators to
// scratch -> 37 GB HBM traffic, 6x slowdown. Do not raise occupancy here.
__global__ __launch_bounds__(512, 2) void gemm_lse256(
    const unsigned char* __restrict__ Xq,
    const unsigned char* __restrict__ Xrq,
    const unsigned char* __restrict__ Wq,
    const unsigned char* __restrict__ Wrq,
    float2* __restrict__ part) {
  __shared__ __align__(16) char lds[2][2][2][8192];

  const int tid = threadIdx.x;
  const int lane = tid & 63;
  const int w = tid >> 6;        // wave 0..7
  const int wm = w >> 2;         // 0..1 : M-half owner
  const int wn = w & 3;          // 0..3 : N-quarter owner
  const int which = blockIdx.y;  // 0 = policy, 1 = reference

  // XCD-aware bijective swizzle: 2000 blocks = 8 XCDs x 250, mb fastest within chunk.
  const int lin = blockIdx.x;
  const int nl = (lin & 7) * 250 + (lin >> 3);
  const int mb = nl & 15;        // 0..15
  const int nb = nl >> 4;        // 0..124

  const unsigned char* A = which ? Xrq : Xq;
  const unsigned char* B = which ? Wrq : Wq;
  float2* pp = part + (size_t)which * BT * NVB;

  // ---- staging addressing (source pre-swizzled to undo read-side XOR) ----
  const int lanep = lane ^ ((lane & 32) >> 4);
  const int rw = w * 16 + (lanep >> 2);     // row within 128-row half
  const int cw = (lanep & 3) * 16;          // byte col within 64-B K-slab
  const unsigned char* Ag = A + (size_t)(mb * 256 + rw) * HDIM + cw;
  const unsigned char* Bg = B + (size_t)(nb * 256 + rw) * HDIM + cw;

#define STAGE(opsel, buf, h, T) do {                                          \
    const unsigned char* _g = (opsel) ? Bg : Ag;                              \
    async_lds16(_g + (size_t)(h) * 128 * HDIM + (T) * 64,                     \
                &lds[buf][opsel][h][0] + w * 1024);                           \
  } while (0)

  // ---- paired fragment read (swizzled b128 -> kk0 + kk1) ----
  const int l15 = lane & 15;
  const int kbyte = (lane >> 4) * 16;
#define FRAGP(d0, d1, halfptr, row) do {                                      \
    int _r = (row);                                                           \
    int _L = _r * 64 + kbyte;                                                 \
    lx2 _v = *(const lx2*)((halfptr) + (_L ^ (((_r >> 3) & 1) << 5)));        \
    d0 = _v.x; d1 = _v.y;                                                     \
  } while (0)

  const char* A0h = &lds[0][0][wm][0];
  const char* A1h = &lds[1][0][wm][0];
  const char* B0h = &lds[0][1][wn >> 1][0];
  const char* B1h = &lds[1][1][wn >> 1][0];
  const int brow = (wn & 1) * 64;

  f32x4 acc[8][4] = {};
  long aF[4][2], bF[4][2];

#define READ_A(base, mi0) do {                                                \
    _Pragma("unroll") for (int mi = 0; mi < 4; ++mi)                          \
      FRAGP(aF[mi][0], aF[mi][1], base, ((mi0) + mi) * 16 + l15);             \
  } while (0)
#define READ_B(base) do {                                                     \
    _Pragma("unroll") for (int ni = 0; ni < 4; ++ni)                          \
      FRAGP(bF[ni][0], bF[ni][1], base, brow + ni * 16 + l15);                \
  } while (0)
#define MFMA_Q(MI0, NI0) do {                                                 \
    __builtin_amdgcn_s_setprio(1);                                            \
    _Pragma("unroll") for (int kk = 0; kk < 2; ++kk)                          \
    _Pragma("unroll") for (int mi = 0; mi < 4; ++mi)                          \
    _Pragma("unroll") for (int ni = 0; ni < 2; ++ni)                          \
      acc[(MI0) + mi][(NI0) + ni] = __builtin_amdgcn_mfma_f32_16x16x32_fp8_fp8( \
          aF[mi][kk], bF[(NI0) + ni][kk], acc[(MI0) + mi][(NI0) + ni], 0, 0, 0); \
    __builtin_amdgcn_s_setprio(0);                                            \
  } while (0)

  // ---- prologue: tile0 (4 halves) + tile1 (B0,B1,A0); A1(t1) staged at iter0 ph1
  STAGE(0, 0, 0, 0); STAGE(0, 0, 1, 0); STAGE(1, 0, 0, 0); STAGE(1, 0, 1, 0);
  STAGE(1, 1, 0, 1); STAGE(1, 1, 1, 1); STAGE(0, 1, 0, 1);
  VMCNT(3);                      // tile0's 4 ops done; t1's 3 in flight
  BAR();

  // ---- main loop: 16 iterations, 2 K-tiles each (tiles 0..31) ----
  for (int i = 0; i < 16; ++i) {
    const int t1 = 2 * i + 1;
    const int se = (2 * i + 2 > 30) ? 30 : 2 * i + 2;  // even stage tile (buf0)
    const int so = (2 * i + 3 > 31) ? 31 : 2 * i + 3;  // odd  stage tile (buf1)

    // phase 1: q0 of tile t0 (buf0)
    READ_A(A0h, 0);
    READ_B(B0h);
    STAGE(0, 1, 1, t1);          // A-half1 of t1
    BAR(); LGKM0();
    MFMA_Q(0, 0);
    BAR();

    // phase 2
    STAGE(1, 0, 0, se);          // B-half0(se)
    BAR(); LGKM0();
    MFMA_Q(0, 2);
    BAR();

    // phase 3
    READ_A(A0h, 4);
    STAGE(1, 0, 1, se);          // B-half1(se)
    BAR(); LGKM0();
    MFMA_Q(4, 0);
    BAR();

    // phase 4
    STAGE(0, 0, 0, se);          // A-half0(se)
    VMCNT(3);                    // tile t1 fully landed
    BAR();
    MFMA_Q(4, 2);
    BAR();

    // phase 5: q0 of tile t1 (buf1)
    READ_A(A1h, 0);
    READ_B(B1h);
    STAGE(0, 0, 1, se);          // A-half1(se)
    BAR(); LGKM0();
    MFMA_Q(0, 0);
    BAR();

    // phase 6
    STAGE(1, 1, 0, so);          // B-half0(so)
    BAR(); LGKM0();
    MFMA_Q(0, 2);
    BAR();

    // phase 7
    READ_A(A1h, 4);
    STAGE(1, 1, 1, so);          // B-half1(so)
    BAR(); LGKM0();
    MFMA_Q(4, 0);
    BAR();

    // phase 8
    STAGE(0, 1, 0, so);          // A-half0(so)
    VMCNT(3);                    // tile se fully landed
    BAR();
    MFMA_Q(4, 2);
    BAR();
  }
  VMCNT(0);                      // drain redundant tail re-stages before LDS reuse
  BAR();

  // ---- fused LSE epilogue over this block's 256 vocab cols ----
  // C/D layout: col = lane&15, row = (lane>>4)*4 + reg. Un-scale by INV_SC.
  float* red = (float*)&lds[0][0][0][0];
#pragma unroll
  for (int mi = 0; mi < 8; ++mi) {
#pragma unroll
    for (int r = 0; r < 4; ++r) {
      float v0 = acc[mi][0][r] * INV_SC;
      float v1 = acc[mi][1][r] * INV_SC;
      float v2 = acc[mi][2][r] * INV_SC;
      float v3 = acc[mi][3][r] * INV_SC;
      float m = fmaxf(fmaxf(v0, v1), fmaxf(v2, v3));
#pragma unroll
      for (int o = 1; o < 16; o <<= 1) m = fmaxf(m, __shfl_xor(m, o, 64));
      float s = __expf(v0 - m) + __expf(v1 - m) + __expf(v2 - m) + __expf(v3 - m);
#pragma unroll
      for (int o = 1; o < 16; o <<= 1) s += __shfl_xor(s, o, 64);
      if (l15 == 0) {
        int row = wm * 128 + mi * 16 + (lane >> 4) * 4 + r;
        red[wn * 256 + row] = m;
        red[1024 + wn * 256 + row] = s;
      }
    }
  }
  __syncthreads();
  if (tid < 256) {
    float m0 = red[tid], m1 = red[256 + tid], m2 = red[512 + tid], m3 = red[768 + tid];
    float M = fmaxf(fmaxf(m0, m1), fmaxf(m2, m3));
    float S = red[1024 + tid] * __expf(m0 - M) + red[1280 + tid] * __expf(m1 - M) +
              red[1536 + tid] * __expf(m2 - M) + red[1792 + tid] * __expf(m3 - M);
    pp[(size_t)(mb * 256 + tid) * NVB + nb] = make_float2(M, S);
  }
#undef STAGE
#undef FRAGP
#undef READ_A
#undef READ_B
#undef MFMA_Q
}

// ---------------------------------------------------------------- exact fp32 target logit: dot(x, W[y])
__global__ void target_logit(const float* __restrict__ x, const float* __restrict__ xr,
                             const float* __restrict__ W, const float* __restrict__ Wr,
                             const int* __restrict__ y, float* __restrict__ tlog) {
  int wid = (blockIdx.x * blockDim.x + threadIdx.x) >> 6;  // 0..8191
  int lane = threadIdx.x & 63;
  int which = wid >> 12;
  int tok = wid & 4095;
  int yy = y[tok];
  int ys = (yy == -100) ? 0 : yy;
  const float* xv = (which ? xr : x) + (size_t)tok * HDIM;
  const float* wv = (which ? Wr : W) + (size_t)ys * HDIM;
  const float4* x4 = (const float4*)xv;
  const float4* w4 = (const float4*)wv;
  float sum = 0.f;
  for (int i = lane; i < HDIM / 4; i += 64) {
    float4 a = x4[i], b = w4[i];
    sum += a.x * b.x + a.y * b.y + a.z * b.z + a.w * b.w;
  }
#pragma unroll
  for (int o = 1; o < 64; o <<= 1) sum += __shfl_xor(sum, o, 64);
  if (lane == 0) tlog[wid] = sum;
}

// ---------------------------------------------------------------- merge partials -> per-token logp
__global__ void lse_combine(const float2* __restrict__ part,
                            const float* __restrict__ tlog,
                            float* __restrict__ ptok) {
  int wid = (blockIdx.x * blockDim.x + threadIdx.x) >> 6;  // 0..8191
  int lane = threadIdx.x & 63;
  const float2* p = part + (size_t)wid * NVB;
  float m = -INFINITY, s = 0.f;
  for (int i = lane; i < NVB; i += 64) {
    float2 v = p[i];
    float M = fmaxf(m, v.x);
    s = s * __expf(m - M) + v.y * __expf(v.x - M);
    m = M;
  }
#pragma unroll
  for (int o = 1; o < 64; o <<= 1) {
    float mo = __shfl_xor(m, o, 64);
    float so = __shfl_xor(s, o, 64);
    float M = fmaxf(m, mo);
    s = s * __expf(m - M) + so * __expf(mo - M);
    m = M;
  }
  if (lane == 0) ptok[wid] = tlog[wid] - (m + logf(s));
}

// ---------------------------------------------------------------- masked per-seq mean + DPO loss
__global__ void final_loss(const float* __restrict__ ptok,
                           const int* __restrict__ y, float* __restrict__ out) {
  __shared__ float rs[256];
  __shared__ float rc[256];
  __shared__ float seq[8];
  int tid = threadIdx.x;
  for (int s = 0; s < 8; ++s) {
    int which = s >> 2, b = s & 3;
    float lsum = 0.f, lcnt = 0.f;
    for (int t = tid; t < 1024; t += 256) {
      int yy = y[b * 1024 + t];
      if (yy != -100) {
        lsum += ptok[which * 4096 + b * 1024 + t];
        lcnt += 1.f;
      }
    }
    rs[tid] = lsum; rc[tid] = lcnt;
    __syncthreads();
    for (int o = 128; o > 0; o >>= 1) {
      if (tid < o) { rs[tid] += rs[tid + o]; rc[tid] += rc[tid + o]; }
      __syncthreads();
    }
    if (tid == 0) seq[s] = rs[0] / rc[0];
    __syncthreads();
  }
  if (tid == 0) {
    float d0 = BETA_F * ((seq[0] - seq[4]) - (seq[2] - seq[6]));
    float d1 = BETA_F * ((seq[1] - seq[5]) - (seq[3] - seq[7]));
    auto sp = [](float a) { return fmaxf(a, 0.f) + log1pf(expf(-fabsf(a))); };
    out[0] = (sp(-d0) + sp(-d1)) * 0.5f;
  }
}

// ---------------------------------------------------------------- launch
extern "C" void kernel_launch(void* const* d_in, const int* in_sizes, int n_in,
                              void* d_out, int out_size, void* d_ws, size_t ws_size,
                              hipStream_t stream) {
  const float* x   = (const float*)d_in[0];
  const float* xr  = (const float*)d_in[1];
  const int*   y   = (const int*)d_in[2];
  const float* Wf  = (const float*)d_in[3];
  const float* Wrf = (const float*)d_in[4];
  float* out = (float*)d_out;

  char* ws = (char*)d_ws;
  size_t off = 0;
  auto alloc = [&](size_t bytes) -> void* {
    void* p = ws + off;
    off = (off + bytes + 255) & ~(size_t)255;
    return p;
  };
  unsigned char* Xq  = (unsigned char*)alloc((size_t)BT * HDIM);
  unsigned char* Xrq = (unsigned char*)alloc((size_t)BT * HDIM);
  unsigned char* Wq  = (unsigned char*)alloc((size_t)VOCAB * HDIM);
  unsigned char* Wrq = (unsigned char*)alloc((size_t)VOCAB * HDIM);
  float2* part = (float2*)alloc((size_t)2 * BT * NVB * sizeof(float2));
  float*  tlog = (float*)alloc((size_t)2 * BT * sizeof(float));
  float*  ptok = (float*)alloc((size_t)2 * BT * sizeof(float));

  cast_fp8_kernel<<<2048, 256, 0, stream>>>(x,  (uint4*)Xq,  BT * HDIM / 16, SCALE_X);
  cast_fp8_kernel<<<2048, 256, 0, stream>>>(xr, (uint4*)Xrq, BT * HDIM / 16, SCALE_X);
  cast_fp8_kernel<<<2048, 256, 0, stream>>>(Wf,  (uint4*)Wq,  VOCAB * HDIM / 16, SCALE_W);
  cast_fp8_kernel<<<2048, 256, 0, stream>>>(Wrf, (uint4*)Wrq, VOCAB * HDIM / 16, SCALE_W);

  dim3 gg(2000, 2);
  gemm_lse256<<<gg, 512, 0, stream>>>(Xq, Xrq, Wq, Wrq, part);

  target_logit<<<2048, 256, 0, stream>>>(x, xr, Wf, Wrf, y, tlog);
  lse_combine<<<2048, 256, 0, stream>>>(part, tlog, ptok);
  final_loss<<<1, 256, 0, stream>>>(ptok, y, out);
}